// Round 2
// baseline (361.104 us; speedup 1.0000x reference)
//
#include <hip/hip_runtime.h>

// FNO2d "kinet" forward. BS=2, H=W=24, WIDTH=20, M1=M2=12, N=576, NPAIR=165600.
// All f32. Output (2,24,24,1) flat = 1152 floats.
//
// Key algebra note (round-1 fix): reference does
//   v_new = v + sum(delta_v * cmask, axis=2)   # axis 2 = FIRST pair index
// so with output index o and partner q:
//   v_new[o] = v[o] + sum_q cmask[o,q] * [ (v[o]-v[q])/2 + vr[o,q]*R[c,q,o] ]
// where R[c,q,o] = +rv[pair(q,o)] if q<o else -rv[pair(o,q)].

#define N_     576
#define NPAIR_ 165600
#define C_     20

__device__ __forceinline__ float gelu_f(float x){
    return 0.5f * x * (1.0f + erff(x * 0.70710678118654752440f));
}

// ---------------- lift: concat(x, gx, gy) @ fc0_w + fc0_b -> (b,c,h,w) ----------------
__global__ void k_lift(const float* __restrict__ xin, const float* __restrict__ w,
                       const float* __restrict__ b, float* __restrict__ xo){
    int t = blockIdx.x*blockDim.x + threadIdx.x;   // t = bb*576 + hw
    if (t >= 2*N_) return;
    int hw = t % N_;
    int h = hw / 24, wc = hw % 24;
    float in[12];
    const float* xp = xin + (size_t)t*10;
    #pragma unroll
    for (int q=0;q<10;q++) in[q] = xp[q];
    in[10] = (float)h  * (1.0f/23.0f);   // gx = linspace(0,1,24)[h]
    in[11] = (float)wc * (1.0f/23.0f);   // gy
    #pragma unroll
    for (int c=0;c<C_;c++){
        float acc = b[c];
        #pragma unroll
        for (int q=0;q<12;q++) acc += in[q]*w[q*C_+c];
        xo[(size_t)(t/N_)*C_*N_ + (size_t)c*N_ + hw] = acc;
    }
}

// ---------------- forward DFT: X[kx=0..23][ky=0..11] per (b,c) ----------------
__global__ void k_fft_fwd(const float* __restrict__ x, float* __restrict__ Xr, float* __restrict__ Xi){
    __shared__ float xt[576], Tr[288], Ti[288], cst[24], snt[24];
    int bc = blockIdx.x;           // b*20+c
    int tid = threadIdx.x;         // 288 threads
    if (tid < 24){
        float s, c;
        sincosf((float)tid * 0.26179938779914943654f, &s, &c);  // 2*pi/24
        cst[tid]=c; snt[tid]=s;
    }
    for (int q=tid;q<576;q+=288) xt[q] = x[(size_t)bc*576+q];
    __syncthreads();
    {   // stage 1: along w:  T[h][ky] = sum_w x[h][w] e^{-i 2pi ky w/24}
        int h = tid/12, ky = tid%12;
        float ar=0.f, ai=0.f;
        for (int w=0;w<24;w++){
            int m = (ky*w) % 24;
            float v = xt[h*24+w];
            ar += v*cst[m];
            ai -= v*snt[m];
        }
        Tr[tid]=ar; Ti[tid]=ai;
    }
    __syncthreads();
    {   // stage 2: along h:  X[kx][ky] = sum_h T[h][ky] e^{-i 2pi kx h/24}
        int kx = tid/12, ky = tid%12;
        float ar=0.f, ai=0.f;
        for (int h=0;h<24;h++){
            int m = (kx*h)%24;
            float tr=Tr[h*12+ky], ti=Ti[h*12+ky];
            float cc=cst[m], ss=snt[m];
            ar += tr*cc + ti*ss;
            ai += ti*cc - tr*ss;
        }
        Xr[(size_t)bc*288 + tid] = ar;
        Xi[(size_t)bc*288 + tid] = ai;
    }
}

// ---------------- mode mixing: out[b,o,kx,ky] = sum_i X[b,i,kx,ky] * W[i,o,...] ----------------
__global__ void k_modemix(const float* __restrict__ Xr, const float* __restrict__ Xi,
                          const float* __restrict__ wr, const float* __restrict__ wi,
                          float* __restrict__ Or, float* __restrict__ Oi){
    int t = blockIdx.x*blockDim.x + threadIdx.x;   // (b,o,kx,ky)
    if (t >= 2*20*288) return;
    int ky = t % 12; int kx = (t/12)%24; int o = (t/288)%20; int bb = t/(288*20);
    int half = (kx>=12) ? 1 : 0; int mx = kx - half*12;
    float ar=0.f, ai=0.f;
    for (int i=0;i<20;i++){
        float xr = Xr[(size_t)(bb*20+i)*288 + kx*12+ky];
        float xi = Xi[(size_t)(bb*20+i)*288 + kx*12+ky];
        size_t widx = ((((size_t)half*20+i)*20+o)*12+mx)*12+ky;
        float wrv = wr[widx], wiv = wi[widx];
        ar += xr*wrv - xi*wiv;
        ai += xr*wiv + xi*wrv;
    }
    Or[(size_t)(bb*20+o)*288 + kx*12+ky] = ar;
    Oi[(size_t)(bb*20+o)*288 + kx*12+ky] = ai;
}

// ---------------- inverse: ifft along kx (complex), then irfft along ky (imag of bin0 discarded) ----------------
__global__ void k_fft_inv(const float* __restrict__ Or, const float* __restrict__ Oi, float* __restrict__ a){
    __shared__ float Fr[288], Fi[288], Yr[288], Yi[288], cst[24], snt[24];
    int bo = blockIdx.x; int tid = threadIdx.x;    // 576 threads
    if (tid < 24){
        float s, c;
        sincosf((float)tid * 0.26179938779914943654f, &s, &c);
        cst[tid]=c; snt[tid]=s;
    }
    if (tid < 288){ Fr[tid]=Or[(size_t)bo*288+tid]; Fi[tid]=Oi[(size_t)bo*288+tid]; }
    __syncthreads();
    if (tid < 288){  // Y[h][ky] = (1/24) sum_kx F[kx][ky] e^{+i 2pi kx h/24}
        int h = tid/12;
        float ar=0.f, ai=0.f;
        for (int kx=0;kx<24;kx++){
            int m=(kx*h)%24;
            float fr=Fr[kx*12 + (tid%12)], fi=Fi[kx*12 + (tid%12)];
            ar += fr*cst[m] - fi*snt[m];
            ai += fr*snt[m] + fi*cst[m];
        }
        Yr[tid]=ar*(1.0f/24.0f); Yi[tid]=ai*(1.0f/24.0f);
    }
    __syncthreads();
    {   // a[h][w] = (1/24)[ Re Y[h,0] + 2 sum_{ky=1..11} Re(Y[h,ky] e^{+i 2pi ky w/24}) ]
        int h = tid/24, w = tid%24;
        float acc = Yr[h*12+0];
        #pragma unroll
        for (int ky=1;ky<12;ky++){
            int m=(ky*w)%24;
            acc += 2.0f*(Yr[h*12+ky]*cst[m] - Yi[h*12+ky]*snt[m]);
        }
        a[(size_t)bo*576 + tid] = acc*(1.0f/24.0f);
    }
}

// ---------------- p = einsum('bchw,oc->bohw', x, w_k) + w_b ----------------
__global__ void k_p(const float* __restrict__ x, const float* __restrict__ wk,
                    const float* __restrict__ wb, float* __restrict__ p){
    int t = blockIdx.x*blockDim.x + threadIdx.x;   // (b,o,hw)
    if (t >= 2*20*N_) return;
    int hw = t % N_; int o = (t/N_)%20; int bb = t/(N_*20);
    float acc = wb[o];
    #pragma unroll
    for (int c=0;c<20;c++) acc += x[(size_t)(bb*20+c)*N_+hw]*wk[o*20+c];
    p[(size_t)(bb*20+o)*N_+hw] = acc;
}

// ---------------- rv step: rv = normalize_c(rv*ori + ori + s), ori = normalize_c(rv_init) ----------------
__global__ void k_rv(const float* __restrict__ rvi, const float* __restrict__ src,
                     float* __restrict__ dst, const float* __restrict__ rs, int k){
    int t = blockIdx.x*blockDim.x + threadIdx.x;   // b*NPAIR + pair
    if (t >= 2*NPAIR_) return;
    int bb = t / NPAIR_; int pr = t % NPAIR_;
    size_t base = (size_t)bb*C_*NPAIR_ + pr;
    float s = rs[k];
    float oi[C_]; float ssqi = 0.f;
    #pragma unroll
    for (int c=0;c<C_;c++){ float v = rvi[base + (size_t)c*NPAIR_]; oi[c]=v; ssqi += v*v; }
    float ni = sqrtf(ssqi);
    float tmp[C_]; float ssq = 0.f;
    #pragma unroll
    for (int c=0;c<C_;c++){
        float orc = oi[c]/ni;
        float rvv = src[base + (size_t)c*NPAIR_];
        float nv = rvv*orc + orc + s;
        tmp[c]=nv; ssq += nv*nv;
    }
    float nn = sqrtf(ssq);
    #pragma unroll
    for (int c=0;c<C_;c++) dst[base + (size_t)c*NPAIR_] = tmp[c]/nn;
}

// ---------------- pairwise: v_r, u_x = exp(-x_r); atomic per-b max of v_r ----------------
__global__ void k_pair(const float* __restrict__ p, const float* __restrict__ a,
                       float* __restrict__ vr, float* __restrict__ ux, float* __restrict__ vmax){
    __shared__ float pi[C_], ai[C_], wred[9];
    int bb = blockIdx.x/N_, i = blockIdx.x%N_;
    int j = threadIdx.x;                         // 576 threads
    if (j < C_){ pi[j]=p[(size_t)(bb*C_+j)*N_+i]; ai[j]=a[(size_t)(bb*C_+j)*N_+i]; }
    __syncthreads();
    float ssx=0.f, ssv=0.f;
    #pragma unroll
    for (int c=0;c<C_;c++){
        float dx = pi[c]-p[(size_t)(bb*C_+c)*N_+j];
        float dv = ai[c]-a[(size_t)(bb*C_+c)*N_+j];
        ssx += dx*dx; ssv += dv*dv;
    }
    float xr  = sqrtf(ssx+1e-12f);
    float vrv = sqrtf(ssv+1e-12f);
    size_t idx = (size_t)(bb*N_+i)*N_ + j;
    ux[idx] = expf(-xr);
    vr[idx] = vrv;
    float m = vrv;
    #pragma unroll
    for (int off=32; off; off>>=1) m = fmaxf(m, __shfl_down(m, off, 64));
    if ((j&63)==0) wred[j>>6] = m;
    __syncthreads();
    if (j==0){
        float mm = wred[0];
        #pragma unroll
        for (int q=1;q<9;q++) mm = fmaxf(mm, wred[q]);
        atomicMax((unsigned int*)&vmax[bb], __float_as_uint(mm));   // v_r >= 0
    }
}

// ---------------- collision update: v_new[o] = v[o] + sum_q cmask*[(v[o]-v[q])/2 + vr*R[c,q,o]] ----------------
__global__ void k_vnew(const float* __restrict__ p, const float* __restrict__ a,
                       const float* __restrict__ vr, const float* __restrict__ ux,
                       const float* __restrict__ rv, const float* __restrict__ vmax,
                       float* __restrict__ xout, int do_gelu){
    int bb = blockIdx.x/N_, i = blockIdx.x%N_;   // i = output index o
    int lane = threadIdx.x;                      // 64 threads = 1 wave
    float vm = vmax[bb];
    const float thr = 0.1f;                      // f32(1.0 - 0.9) weak-typed in JAX
    float cnt=0.f, sv[C_], rA[C_];
    #pragma unroll
    for (int c=0;c<C_;c++){ sv[c]=0.f; rA[c]=0.f; }
    const float* vrow = vr + (size_t)(bb*N_+i)*N_;
    const float* urow = ux + (size_t)(bb*N_+i)*N_;
    size_t rbase = (size_t)bb*C_*NPAIR_;
    for (int j=lane; j<N_; j+=64){               // j = partner index q
        if (j==i) continue;                      // diagonal contributes exactly 0
        float vrij = vrow[j];
        float m = (vrij/vm)*urow[j];
        if (m > thr){
            cnt += 1.0f;
            // R[c, j, i]: +rv[pair(j,i)] if j<i, -rv[pair(i,j)] if j>i
            int pidx; float sgn;
            if (j<i){ pidx = j*(2*N_-j-1)/2 + (i-j-1); sgn= 1.0f; }
            else    { pidx = i*(2*N_-i-1)/2 + (j-i-1); sgn=-1.0f; }
            float vrs = sgn*vrij;
            #pragma unroll
            for (int c=0;c<C_;c++){
                sv[c] += a[(size_t)(bb*C_+c)*N_+j];
                rA[c] += vrs * rv[rbase + (size_t)c*NPAIR_ + pidx];
            }
        }
    }
    #pragma unroll
    for (int off=32; off; off>>=1){
        cnt += __shfl_xor(cnt, off, 64);
        #pragma unroll
        for (int c=0;c<C_;c++){
            sv[c] += __shfl_xor(sv[c], off, 64);
            rA[c] += __shfl_xor(rA[c], off, 64);
        }
    }
    if (lane < C_){
        int c = lane;
        float vi = a[(size_t)(bb*C_+c)*N_+i];
        // v_new[i] = v[i] + 0.5*(cnt*v[i] - sum_q v[q]) + sum_q vr*R[c,q,i]
        float vnew = vi + 0.5f*(cnt*vi - sv[c]) + rA[c];
        float xn = p[(size_t)(bb*C_+c)*N_+i] + vnew;
        if (do_gelu) xn = gelu_f(xn);
        xout[(size_t)(bb*C_+c)*N_+i] = xn;
    }
}

// ---------------- head: gelu(x@fc1+b1)@fc2+b2, per position ----------------
__global__ void k_head(const float* __restrict__ x, const float* __restrict__ w1,
                       const float* __restrict__ b1, const float* __restrict__ w2,
                       const float* __restrict__ b2, float* __restrict__ out){
    __shared__ float xi[C_];
    __shared__ float part[2];
    int pos = blockIdx.x; int bb = pos/N_, hw = pos%N_;
    int t = threadIdx.x;                         // 128 threads
    if (t < C_) xi[t] = x[(size_t)(bb*C_+t)*N_+hw];
    __syncthreads();
    float h = b1[t];
    #pragma unroll
    for (int c=0;c<C_;c++) h += xi[c]*w1[c*128+t];
    float g = gelu_f(h) * w2[t];
    #pragma unroll
    for (int off=32; off; off>>=1) g += __shfl_down(g, off, 64);
    if ((t&63)==0) part[t>>6] = g;
    __syncthreads();
    if (t==0) out[pos] = part[0] + part[1] + b2[0];
}

extern "C" void kernel_launch(void* const* d_in, const int* in_sizes, int n_in,
                              void* d_out, int out_size, void* d_ws, size_t ws_size,
                              hipStream_t stream) {
    const float* in_x   = (const float*)d_in[0];
    // d_in[1] (v) is dead in the reference forward
    const float* fc0_w  = (const float*)d_in[2];
    const float* fc0_b  = (const float*)d_in[3];
    const float* sc_wr  = (const float*)d_in[4];
    const float* sc_wi  = (const float*)d_in[5];
    const float* w_k    = (const float*)d_in[6];
    const float* w_b    = (const float*)d_in[7];
    const float* fc1_w  = (const float*)d_in[8];
    const float* fc1_b  = (const float*)d_in[9];
    const float* fc2_w  = (const float*)d_in[10];
    const float* fc2_b  = (const float*)d_in[11];
    const float* rv_init= (const float*)d_in[12];
    const float* rv_s   = (const float*)d_in[13];
    float* out = (float*)d_out;
    float* ws  = (float*)d_ws;

    // workspace layout (floats); total 8,066,312 floats = 32.3 MB
    float* x_cur = ws;
    float* p     = ws + 23040;
    float* a     = ws + 46080;
    float* Xr    = ws + 69120;
    float* Xi    = ws + 80640;
    float* Or    = ws + 92160;
    float* Oi    = ws + 103680;
    float* vr    = ws + 115200;
    float* ux    = ws + 778752;
    float* rvst  = ws + 1442304;
    float* vmax  = ws + 8066304;   // [4 layers][2 batches]

    hipMemsetAsync(vmax, 0, 8*sizeof(float), stream);

    k_lift<<<dim3((2*N_+63)/64), 64, 0, stream>>>(in_x, fc0_w, fc0_b, x_cur);

    for (int k=0;k<4;k++){
        const size_t woff = (size_t)k*2*20*20*144;
        k_fft_fwd<<<40, 288, 0, stream>>>(x_cur, Xr, Xi);
        k_modemix<<<(2*20*288+63)/64, 64, 0, stream>>>(Xr, Xi, sc_wr+woff, sc_wi+woff, Or, Oi);
        k_fft_inv<<<40, 576, 0, stream>>>(Or, Oi, a);
        k_p<<<(2*20*N_+63)/64, 64, 0, stream>>>(x_cur, w_k + k*400, w_b + k*20, p);
        k_rv<<<(2*NPAIR_+63)/64, 64, 0, stream>>>(rv_init, (k==0) ? rv_init : rvst, rvst, rv_s, k);
        k_pair<<<2*N_, N_, 0, stream>>>(p, a, vr, ux, vmax + 2*k);
        k_vnew<<<2*N_, 64, 0, stream>>>(p, a, vr, ux, rvst, vmax + 2*k, x_cur, (k<3) ? 1 : 0);
    }

    k_head<<<2*N_, 128, 0, stream>>>(x_cur, fc1_w, fc1_b, fc2_w, fc2_b, out);
}

// Round 3
// 284.685 us; speedup vs baseline: 1.2684x; 1.2684x over previous
//
#include <hip/hip_runtime.h>

// FNO2d "kinet" forward. BS=2, H=W=24, WIDTH=20, M1=M2=12, N=576, NPAIR=165600.
// All f32. Output (2,24,24,1) flat = 1152 floats.
//
// Collision algebra (verified round 2):
//   v_new[o] = v[o] + sum_q cmask[o,q] * [ (v[o]-v[q])/2 + vr[o,q]*R[c,q,o] ]
//   R[c,q,o] = +rv[pair(q,o)] if q<o else -rv[pair(o,q)].
//
// Round-3 layout change: rv state, p, a are PAIR-MAJOR ([...][20], 80B rows)
// so per-hit channel reads are 1-2 cache lines instead of 20.

#define N_     576
#define NPAIR_ 165600
#define C_     20

__device__ __forceinline__ float gelu_f(float x){
    return 0.5f * x * (1.0f + erff(x * 0.70710678118654752440f));
}

// ---------------- lift: concat(x, gx, gy) @ fc0_w + fc0_b -> (b,c,h,w) ----------------
__global__ void k_lift(const float* __restrict__ xin, const float* __restrict__ w,
                       const float* __restrict__ b, float* __restrict__ xo){
    int t = blockIdx.x*blockDim.x + threadIdx.x;   // t = bb*576 + hw
    if (t >= 2*N_) return;
    int hw = t % N_;
    int h = hw / 24, wc = hw % 24;
    float in[12];
    const float* xp = xin + (size_t)t*10;
    #pragma unroll
    for (int q=0;q<10;q++) in[q] = xp[q];
    in[10] = (float)h  * (1.0f/23.0f);
    in[11] = (float)wc * (1.0f/23.0f);
    #pragma unroll
    for (int c=0;c<C_;c++){
        float acc = b[c];
        #pragma unroll
        for (int q=0;q<12;q++) acc += in[q]*w[q*C_+c];
        xo[(size_t)(t/N_)*C_*N_ + (size_t)c*N_ + hw] = acc;
    }
}

// ---------------- forward DFT: X[kx=0..23][ky=0..11] per (b,c) ----------------
__global__ void k_fft_fwd(const float* __restrict__ x, float* __restrict__ Xr, float* __restrict__ Xi){
    __shared__ float xt[576], Tr[288], Ti[288], cst[24], snt[24];
    int bc = blockIdx.x;           // b*20+c
    int tid = threadIdx.x;         // 288 threads
    if (tid < 24){
        float s, c;
        sincosf((float)tid * 0.26179938779914943654f, &s, &c);  // 2*pi/24
        cst[tid]=c; snt[tid]=s;
    }
    for (int q=tid;q<576;q+=288) xt[q] = x[(size_t)bc*576+q];
    __syncthreads();
    {   // stage 1: along w
        int h = tid/12, ky = tid%12;
        float ar=0.f, ai=0.f;
        for (int w=0;w<24;w++){
            int m = (ky*w) % 24;
            float v = xt[h*24+w];
            ar += v*cst[m];
            ai -= v*snt[m];
        }
        Tr[tid]=ar; Ti[tid]=ai;
    }
    __syncthreads();
    {   // stage 2: along h
        int kx = tid/12, ky = tid%12;
        float ar=0.f, ai=0.f;
        for (int h=0;h<24;h++){
            int m = (kx*h)%24;
            float tr=Tr[h*12+ky], ti=Ti[h*12+ky];
            float cc=cst[m], ss=snt[m];
            ar += tr*cc + ti*ss;
            ai += ti*cc - tr*ss;
        }
        Xr[(size_t)bc*288 + tid] = ar;
        Xi[(size_t)bc*288 + tid] = ai;
    }
}

// ------- fused mode-mix + inverse FFT; writes a_t pair-major [b][n][20] -------
__global__ void k_fft_inv(const float* __restrict__ Xr, const float* __restrict__ Xi,
                          const float* __restrict__ wr, const float* __restrict__ wi,
                          float* __restrict__ a_t){
    __shared__ float Fr[288], Fi[288], Yr[288], Yi[288], cst[24], snt[24];
    int bo = blockIdx.x; int bb = bo/20, o = bo%20;
    int tid = threadIdx.x;    // 576 threads
    if (tid < 24){
        float s, c;
        sincosf((float)tid * 0.26179938779914943654f, &s, &c);
        cst[tid]=c; snt[tid]=s;
    }
    if (tid < 288){   // mode mixing: F[kx][ky] = sum_i X[b,i,kx,ky]*W[i,o,...]
        int ky = tid%12, kx = tid/12;
        int half = (kx>=12) ? 1 : 0; int mx = kx - half*12;
        float ar=0.f, ai=0.f;
        for (int i=0;i<20;i++){
            float xr = Xr[(size_t)(bb*20+i)*288 + tid];
            float xi = Xi[(size_t)(bb*20+i)*288 + tid];
            size_t widx = ((((size_t)half*20+i)*20+o)*12+mx)*12+ky;
            float wrv = wr[widx], wiv = wi[widx];
            ar += xr*wrv - xi*wiv;
            ai += xr*wiv + xi*wrv;
        }
        Fr[tid]=ar; Fi[tid]=ai;
    }
    __syncthreads();
    if (tid < 288){  // Y[h][ky] = (1/24) sum_kx F[kx][ky] e^{+i 2pi kx h/24}
        int h = tid/12;
        float ar=0.f, ai=0.f;
        for (int kx=0;kx<24;kx++){
            int m=(kx*h)%24;
            float fr=Fr[kx*12 + (tid%12)], fi=Fi[kx*12 + (tid%12)];
            ar += fr*cst[m] - fi*snt[m];
            ai += fr*snt[m] + fi*cst[m];
        }
        Yr[tid]=ar*(1.0f/24.0f); Yi[tid]=ai*(1.0f/24.0f);
    }
    __syncthreads();
    {   // a[h][w] = (1/24)[ Re Y[h,0] + 2 sum_{ky=1..11} Re(Y[h,ky] e^{+i 2pi ky w/24}) ]
        int h = tid/24, w = tid%24;
        float acc = Yr[h*12+0];
        #pragma unroll
        for (int ky=1;ky<12;ky++){
            int m=(ky*w)%24;
            acc += 2.0f*(Yr[h*12+ky]*cst[m] - Yi[h*12+ky]*snt[m]);
        }
        a_t[((size_t)bb*N_ + tid)*C_ + o] = acc*(1.0f/24.0f);   // imag(ky=0) discarded by irfft
    }
}

// ------- p_t = einsum('bchw,oc->bohw', x, w_k)+w_b, pair-major [b][n][20] -------
__global__ void k_p(const float* __restrict__ x, const float* __restrict__ wk,
                    const float* __restrict__ wb, float* __restrict__ p_t){
    __shared__ float swk[400], swb[C_];
    int tid = threadIdx.x;                        // 64 threads
    for (int q=tid;q<400;q+=64) swk[q]=wk[q];
    if (tid < C_) swb[tid]=wb[tid];
    __syncthreads();
    int t = blockIdx.x*64 + tid;                  // (b,hw)
    if (t >= 2*N_) return;
    int bb = t / N_, hw = t % N_;
    float xi[C_];
    #pragma unroll
    for (int c=0;c<C_;c++) xi[c] = x[(size_t)(bb*C_+c)*N_+hw];
    float accv[C_];
    #pragma unroll
    for (int o=0;o<C_;o++){
        float acc = swb[o];
        #pragma unroll
        for (int c=0;c<C_;c++) acc += xi[c]*swk[o*C_+c];
        accv[o]=acc;
    }
    float4* dst = (float4*)(p_t + (size_t)t*C_);
    #pragma unroll
    for (int q=0;q<5;q++) dst[q] = make_float4(accv[4*q],accv[4*q+1],accv[4*q+2],accv[4*q+3]);
}

// ------- rv step, pair-major state [b][pair][20], IN-PLACE across layers -------
// ori = normalize_c(rv_init);  state = normalize_c(state*ori + ori + s)
__global__ void k_rv(const float* __restrict__ rvi, float* rvt,
                     const float* __restrict__ rs, int k){
    int t = blockIdx.x*blockDim.x + threadIdx.x;   // b*NPAIR + pair
    if (t >= 2*NPAIR_) return;
    int bb = t / NPAIR_; int pr = t % NPAIR_;
    size_t ibase = (size_t)bb*C_*NPAIR_ + pr;
    float s = rs[k];
    float oi[C_]; float ssqi = 0.f;
    #pragma unroll
    for (int c=0;c<C_;c++){ float v = rvi[ibase + (size_t)c*NPAIR_]; oi[c]=v; ssqi += v*v; }
    float ni = sqrtf(ssqi);
    float st[C_];
    if (k==0){
        #pragma unroll
        for (int c=0;c<C_;c++) st[c]=oi[c];
    } else {
        const float4* src4 = (const float4*)(rvt + (size_t)t*C_);
        float4 v4[5];
        #pragma unroll
        for (int q=0;q<5;q++) v4[q]=src4[q];
        #pragma unroll
        for (int q=0;q<5;q++){ st[4*q]=v4[q].x; st[4*q+1]=v4[q].y; st[4*q+2]=v4[q].z; st[4*q+3]=v4[q].w; }
    }
    float ssq = 0.f;
    #pragma unroll
    for (int c=0;c<C_;c++){
        float orc = oi[c]/ni;
        float nv = st[c]*orc + orc + s;
        st[c]=nv; ssq += nv*nv;
    }
    float nn = sqrtf(ssq);
    float4* dst4 = (float4*)(rvt + (size_t)t*C_);
    #pragma unroll
    for (int q=0;q<5;q++)
        dst4[q] = make_float4(st[4*q]/nn, st[4*q+1]/nn, st[4*q+2]/nn, st[4*q+3]/nn);
}

// ---------------- pairwise: v_r, u_x = exp(-x_r); atomic per-b max of v_r ----------------
__global__ void k_pair(const float* __restrict__ p_t, const float* __restrict__ a_t,
                       float* __restrict__ vr, float* __restrict__ ux, float* __restrict__ vmax){
    __shared__ float pi[C_], ai[C_], wred[9];
    int bb = blockIdx.x/N_, i = blockIdx.x%N_;
    int j = threadIdx.x;                         // 576 threads
    if (j < C_){ pi[j]=p_t[((size_t)bb*N_+i)*C_+j]; ai[j]=a_t[((size_t)bb*N_+i)*C_+j]; }
    __syncthreads();
    const float4* pj4 = (const float4*)(p_t + ((size_t)bb*N_+j)*C_);
    const float4* aj4 = (const float4*)(a_t + ((size_t)bb*N_+j)*C_);
    float ssx=0.f, ssv=0.f;
    #pragma unroll
    for (int q=0;q<5;q++){
        float4 pv = pj4[q], av = aj4[q];
        float dx, dv;
        dx = pi[4*q+0]-pv.x; dv = ai[4*q+0]-av.x; ssx += dx*dx; ssv += dv*dv;
        dx = pi[4*q+1]-pv.y; dv = ai[4*q+1]-av.y; ssx += dx*dx; ssv += dv*dv;
        dx = pi[4*q+2]-pv.z; dv = ai[4*q+2]-av.z; ssx += dx*dx; ssv += dv*dv;
        dx = pi[4*q+3]-pv.w; dv = ai[4*q+3]-av.w; ssx += dx*dx; ssv += dv*dv;
    }
    float xr  = sqrtf(ssx+1e-12f);
    float vrv = sqrtf(ssv+1e-12f);
    size_t idx = (size_t)(bb*N_+i)*N_ + j;
    ux[idx] = expf(-xr);
    vr[idx] = vrv;
    float m = vrv;
    #pragma unroll
    for (int off=32; off; off>>=1) m = fmaxf(m, __shfl_down(m, off, 64));
    if ((j&63)==0) wred[j>>6] = m;
    __syncthreads();
    if (j==0){
        float mm = wred[0];
        #pragma unroll
        for (int q=1;q<9;q++) mm = fmaxf(mm, wred[q]);
        atomicMax((unsigned int*)&vmax[bb], __float_as_uint(mm));   // v_r >= 0
    }
}

// -------- collision update: v_new[o] = v[o] + sum_q cmask*[(v[o]-v[q])/2 + vr*R[c,q,o]] --------
__global__ void k_vnew(const float* __restrict__ p_t, const float* __restrict__ a_t,
                       const float* __restrict__ vr, const float* __restrict__ ux,
                       const float* __restrict__ rvt, const float* __restrict__ vmax,
                       float* __restrict__ xout, int do_gelu){
    int bb = blockIdx.x/N_, i = blockIdx.x%N_;   // i = output index o
    int lane = threadIdx.x;                      // 64 threads = 1 wave
    float vm = vmax[bb];
    const float thr = 0.1f;                      // f32(1.0 - 0.9) weak-typed in JAX
    float cnt=0.f, sv[C_], rA[C_];
    #pragma unroll
    for (int c=0;c<C_;c++){ sv[c]=0.f; rA[c]=0.f; }
    const float* vrow = vr + (size_t)(bb*N_+i)*N_;
    const float* urow = ux + (size_t)(bb*N_+i)*N_;
    for (int j=lane; j<N_; j+=64){               // j = partner index q
        if (j==i) continue;                      // diagonal contributes exactly 0
        float vrij = vrow[j];
        float m = (vrij/vm)*urow[j];
        if (m > thr){
            cnt += 1.0f;
            // R[c, j, i]: +rv[pair(j,i)] if j<i, -rv[pair(i,j)] if j>i
            int pidx; float sgn;
            if (j<i){ pidx = j*(2*N_-j-1)/2 + (i-j-1); sgn= 1.0f; }
            else    { pidx = i*(2*N_-i-1)/2 + (j-i-1); sgn=-1.0f; }
            float vrs = sgn*vrij;
            const float4* rp = (const float4*)(rvt + ((size_t)bb*NPAIR_ + pidx)*C_);
            const float4* ap = (const float4*)(a_t + ((size_t)bb*N_ + j)*C_);
            #pragma unroll
            for (int q=0;q<5;q++){
                float4 rr = rp[q], aa = ap[q];
                sv[4*q+0] += aa.x; rA[4*q+0] += vrs*rr.x;
                sv[4*q+1] += aa.y; rA[4*q+1] += vrs*rr.y;
                sv[4*q+2] += aa.z; rA[4*q+2] += vrs*rr.z;
                sv[4*q+3] += aa.w; rA[4*q+3] += vrs*rr.w;
            }
        }
    }
    #pragma unroll
    for (int off=32; off; off>>=1){
        cnt += __shfl_xor(cnt, off, 64);
        #pragma unroll
        for (int c=0;c<C_;c++){
            sv[c] += __shfl_xor(sv[c], off, 64);
            rA[c] += __shfl_xor(rA[c], off, 64);
        }
    }
    if (lane < C_){
        int c = lane;
        float vi = a_t[((size_t)bb*N_+i)*C_+c];
        float vnew = vi + 0.5f*(cnt*vi - sv[c]) + rA[c];
        float xn = p_t[((size_t)bb*N_+i)*C_+c] + vnew;
        if (do_gelu) xn = gelu_f(xn);
        xout[(size_t)(bb*C_+c)*N_+i] = xn;       // channel-major for fft/p/head
    }
}

// ---------------- head: gelu(x@fc1+b1)@fc2+b2, per position ----------------
__global__ void k_head(const float* __restrict__ x, const float* __restrict__ w1,
                       const float* __restrict__ b1, const float* __restrict__ w2,
                       const float* __restrict__ b2, float* __restrict__ out){
    __shared__ float xi[C_];
    __shared__ float part[2];
    int pos = blockIdx.x; int bb = pos/N_, hw = pos%N_;
    int t = threadIdx.x;                         // 128 threads
    if (t < C_) xi[t] = x[(size_t)(bb*C_+t)*N_+hw];
    __syncthreads();
    float h = b1[t];
    #pragma unroll
    for (int c=0;c<C_;c++) h += xi[c]*w1[c*128+t];
    float g = gelu_f(h) * w2[t];
    #pragma unroll
    for (int off=32; off; off>>=1) g += __shfl_down(g, off, 64);
    if ((t&63)==0) part[t>>6] = g;
    __syncthreads();
    if (t==0) out[pos] = part[0] + part[1] + b2[0];
}

extern "C" void kernel_launch(void* const* d_in, const int* in_sizes, int n_in,
                              void* d_out, int out_size, void* d_ws, size_t ws_size,
                              hipStream_t stream) {
    const float* in_x   = (const float*)d_in[0];
    // d_in[1] (v) is dead in the reference forward
    const float* fc0_w  = (const float*)d_in[2];
    const float* fc0_b  = (const float*)d_in[3];
    const float* sc_wr  = (const float*)d_in[4];
    const float* sc_wi  = (const float*)d_in[5];
    const float* w_k    = (const float*)d_in[6];
    const float* w_b    = (const float*)d_in[7];
    const float* fc1_w  = (const float*)d_in[8];
    const float* fc1_b  = (const float*)d_in[9];
    const float* fc2_w  = (const float*)d_in[10];
    const float* fc2_b  = (const float*)d_in[11];
    const float* rv_init= (const float*)d_in[12];
    const float* rv_s   = (const float*)d_in[13];
    float* out = (float*)d_out;
    float* ws  = (float*)d_ws;

    // workspace layout (floats); total 8,043,272 floats = 32.2 MB
    float* x_cur = ws;                 // 23040  [b][c][n]
    float* p_t   = ws + 23040;         // 23040  [b][n][20]
    float* a_t   = ws + 46080;         // 23040  [b][n][20]
    float* Xr    = ws + 69120;         // 11520
    float* Xi    = ws + 80640;         // 11520
    float* vr    = ws + 92160;         // 663552
    float* ux    = ws + 755712;        // 663552
    float* rvt   = ws + 1419264;       // 6624000  [b][pair][20], in-place state
    float* vmax  = ws + 8043264;       // 8 = [4 layers][2 batches]

    hipMemsetAsync(vmax, 0, 8*sizeof(float), stream);

    k_lift<<<dim3((2*N_+63)/64), 64, 0, stream>>>(in_x, fc0_w, fc0_b, x_cur);

    for (int k=0;k<4;k++){
        const size_t woff = (size_t)k*2*20*20*144;
        k_fft_fwd<<<40, 288, 0, stream>>>(x_cur, Xr, Xi);
        k_fft_inv<<<40, 576, 0, stream>>>(Xr, Xi, sc_wr+woff, sc_wi+woff, a_t);
        k_p<<<(2*N_+63)/64, 64, 0, stream>>>(x_cur, w_k + k*400, w_b + k*20, p_t);
        k_rv<<<(2*NPAIR_+63)/64, 64, 0, stream>>>(rv_init, rvt, rv_s, k);
        k_pair<<<2*N_, N_, 0, stream>>>(p_t, a_t, vr, ux, vmax + 2*k);
        k_vnew<<<2*N_, 64, 0, stream>>>(p_t, a_t, vr, ux, rvt, vmax + 2*k, x_cur, (k<3) ? 1 : 0);
    }

    k_head<<<2*N_, 128, 0, stream>>>(x_cur, fc1_w, fc1_b, fc2_w, fc2_b, out);
}